// Round 1
// 64.285 us; speedup vs baseline: 1.0631x; 1.0631x over previous
//
#include <hip/hip_runtime.h>
#include <math.h>

// 14-qubit, 6-layer RX+CNOT-ring circuit, batch 512 — fully collapsed form.
//
// Verified chain (R3/R4/R7/R9/R10/R11 passed end-to-end):
//   out[b][q] = 2^-14 * sum_u [ cos(A_u) C^q_u + sin(A_u) S^q_u ]
//   C^q_u + i S^q_u = sum_{k: pext(k,r_q)=u} e^{i DTheta_k}
//   DTheta_k = sum_{g: <r_q,m_g> odd} (-1)^{popc(k&m_g)} theta_g
//
// R13: single fused kernel. R12's two launches serialized through a global
// tab round-trip; rocprof shows the measured window is dominated by a fixed
// 39 us harness ws-poison fill, so the controllable cost is launch count +
// the 14-block latency-bound build. The bin tables are tiny (<= 2 KB per q),
// so each block REBUILDS its own q-table in LDS (byte-identical math to the
// verified build_q: same t enumeration, same NREP replica merge order) and
// immediately consumes it for a 32-batch slice. Grid = 14 q x 16 slices =
// 224 blocks x 1024 threads: no grid sync, no global tab, d_ws unused.
// Phase B = verified qout inner loop, restructured per-wave (2 batches per
// wave, reduction wave-local). SESSION RULE intact: each out[b][q] written
// by exactly one wave of exactly one block.

#define NQ 14
#define DIM 16384
#define NLAYERS 6
#define NGATES (NLAYERS * NQ)   // 84
#define BATCH 512
#define TB 1024                 // threads per block
#define NREP 16                 // bin replicas, one per wave
#define NSLICE 16               // batch slices
#define SLICE_B (BATCH / NSLICE)        // 32 batches per block
#define B_PER_WAVE (SLICE_B * 64 / TB)  // 2 batches per wave

constexpr int cpopc(unsigned v) { int c = 0; while (v) { c += (int)(v & 1u); v >>= 1; } return c; }

constexpr unsigned cpext(unsigned v, unsigned m) {
    // extract bits of v at set positions of m, LSB-first
    unsigned r = 0; int b = 0;
    for (int pos = 0; pos < 16; ++pos)
        if ((m >> pos) & 1u) { r |= ((v >> pos) & 1u) << b; ++b; }
    return r;
}

struct Tabs {
    unsigned short m[NGATES];        // gate masks (k-bit-position space)
    unsigned short r[NQ];            // readout lag masks
    int p[NQ];                       // popc(r[q])
    int off[NQ + 1];                 // bin-table offsets (prefix sums of 2^p)
    unsigned char qb[NQ][NQ];        // qubit index per set bit of r (LSB-first)
    int ng[NQ];                      // # gates with odd overlap vs r[q]
    unsigned short gmask[NQ][NGATES];
    unsigned char  gidx[NQ][NGATES];
};

constexpr Tabs gen_tabs() {
    Tabs T{};
    unsigned short C[NQ] = {}, R[NQ] = {};
    for (int q = 0; q < NQ; ++q) { C[q] = (unsigned short)(1u << (NQ - 1 - q)); R[q] = C[q]; }
    for (int l = 0; l < NLAYERS; ++l) {
        for (int q = 0; q < NQ; ++q) T.m[l * NQ + q] = C[q];
        for (int g = 0; g < NQ; ++g) {           // sequential — matches all passing rounds
            int t = (g + 1) % NQ;
            C[g] ^= C[t];
            R[t] ^= R[g];
        }
    }
    for (int q = 0; q < NQ; ++q) T.r[q] = R[q];
    for (int q = 0; q < NQ; ++q) {
        int cnt = 0;
        for (int pos = 0; pos < NQ; ++pos)
            if ((R[q] >> pos) & 1u) { T.qb[q][cnt] = (unsigned char)(NQ - 1 - pos); ++cnt; }
        T.p[q] = cnt;
    }
    T.off[0] = 0;
    for (int q = 0; q < NQ; ++q) T.off[q + 1] = T.off[q] + (1 << T.p[q]);
    for (int q = 0; q < NQ; ++q) {
        int n = 0;
        for (int g = 0; g < NGATES; ++g) {
            if (cpopc((unsigned)(T.m[g] & R[q])) & 1) {
                T.gmask[q][n] = T.m[g];
                T.gidx[q][n]  = (unsigned char)g;
                ++n;
            }
        }
        T.ng[q] = n;
    }
    return T;
}
constexpr Tabs TAB = gen_tabs();

constexpr int calc_maxp() { int m = 0; for (int q = 0; q < NQ; ++q) if (TAB.p[q] > m) m = TAB.p[q]; return m; }
constexpr int calc_minp() { int m = 99; for (int q = 0; q < NQ; ++q) if (TAB.p[q] < m) m = TAB.p[q]; return m; }
constexpr int MAXP  = calc_maxp();
constexpr int MINP  = calc_minp();
constexpr int TOTAL = TAB.off[NQ];
static_assert(MAXP <= 8, "u = t & (2^p-1) needs p <= 10; replicas sized for p <= 8");
static_assert(MINP >= 1, "r mask must be nonzero");

// ---- recursive gate product: literal masks, register buckets only ----
template<int Q, int I>
__device__ __forceinline__ void gates(const float2* __restrict__ w, int t,
                                      float (&Bx)[16], float (&By)[16])
{
    if constexpr (I < TAB.ng[Q]) {
        constexpr unsigned r  = TAB.r[Q];
        constexpr unsigned nr = (~r) & 0x3FFFu;
        constexpr int      p  = TAB.p[Q];
        constexpr unsigned mg = TAB.gmask[Q][I];
        constexpr unsigned Ag = cpext(mg, r);                         // p bits
        constexpr unsigned Bg = cpext(mg, nr);                        // 14-p bits
        constexpr unsigned Mg = Ag | ((Bg & ((1u << (10 - p)) - 1u)) << p); // 10-bit
        constexpr unsigned Hg = (Bg >> (10 - p)) & 15u;               // 4-bit class
        const float2 wv = w[I];                       // ds_read_b64 broadcast
        const float si = (__popc((unsigned)t & Mg) & 1) ? -wv.y : wv.y;
        const float c  = wv.x;
        const float nx = Bx[Hg] * c - By[Hg] * si;
        const float ny = Bx[Hg] * si + By[Hg] * c;
        Bx[Hg] = nx; By[Hg] = ny;
        gates<Q, I + 1>(w, t, Bx, By);
    }
}

template<int Q>
__device__ __forceinline__ void build_q(const float2* __restrict__ w,
                                        float* __restrict__ binC,
                                        float* __restrict__ binS, int t)
{
    constexpr int      p       = TAB.p[Q];
    constexpr unsigned lowmask = (1u << p) - 1u;

    // phase 1: 16 complex buckets B[h] = e^{i P[h]} (t-part signs)
    float Bx[16], By[16];
    #pragma unroll
    for (int h = 0; h < 16; ++h) { Bx[h] = 1.0f; By[h] = 0.0f; }
    gates<Q, 0>(w, t, Bx, By);

    // phase 2: product-WHT -> B[kk] = e^{i DTheta(k(t,kk))} (R10-verified)
    #pragma unroll
    for (int s = 1; s < 16; s <<= 1) {
        #pragma unroll
        for (int h = 0; h < 16; ++h) {
            if (!(h & s)) {
                const int h1 = h | s;
                const float p1 = Bx[h] * Bx[h1], p2 = By[h] * By[h1];
                const float p3 = Bx[h] * By[h1], p4 = By[h] * Bx[h1];
                Bx[h]  = p1 - p2;  By[h]  = p3 + p4;   // A*B
                Bx[h1] = p1 + p2;  By[h1] = p4 - p3;   // A*conj(B)
            }
        }
    }

    // phase 3: all 16 kk share bin u = t & lowmask -> register sum
    float fx = 0.0f, fy = 0.0f;
    #pragma unroll
    for (int h = 0; h < 16; ++h) { fx += Bx[h]; fy += By[h]; }

    const unsigned u   = (unsigned)t & lowmask;
    const int      rep = t >> 6;                 // per-wave replica
    float* bc = binC + (rep << MAXP);
    float* bs = binS + (rep << MAXP);

    if constexpr (p >= 6) {
        // lanes of a wave have distinct u; waves separated by replicas:
        // one plain store pair per thread, no shuffles, no atomics.
        bc[u] = fx;
        bs[u] = fy;
    } else {
        // group mates differ in lane bits p..5: short shuffle tree, lead writes
        constexpr unsigned dm = 63u & ~lowmask;
        #pragma unroll
        for (int bb = p; bb < 6; ++bb) {
            fx += __shfl_xor(fx, 1 << bb, 64);
            fy += __shfl_xor(fy, 1 << bb, 64);
        }
        if (((unsigned)t & dm) == 0u) {
            bc[u] = fx;
            bs[u] = fy;
        }
    }
}

// ---- fused per-block pipeline: build q-table in LDS, consume for 32 batches ----
template<int Q>
__device__ __forceinline__ void run_q(const float2* __restrict__ w,
                                      float* __restrict__ binC,
                                      float* __restrict__ binS,
                                      float* __restrict__ tabC,
                                      float* __restrict__ tabS,
                                      const float* __restrict__ sxAll,
                                      float* __restrict__ out,
                                      int slice, int t)
{
    build_q<Q>(w, binC, binS, t);
    __syncthreads();

    // merge replicas into final LDS table (same fixed order as R12 — deterministic)
    constexpr int p  = TAB.p[Q];
    constexpr int nb = 1 << p;
    for (int i = t; i < nb; i += TB) {
        float sc = 0.0f, ss = 0.0f;
        #pragma unroll
        for (int rp = 0; rp < NREP; ++rp) {
            sc += binC[(rp << MAXP) + i];
            ss += binS[(rp << MAXP) + i];
        }
        tabC[i] = sc;
        tabS[i] = ss;
    }
    __syncthreads();

    // phase B: each wave owns B_PER_WAVE batches; reduction stays in-wave.
    const int wave = t >> 6;
    const int lane = t & 63;
    #pragma unroll
    for (int bb = 0; bb < B_PER_WAVE; ++bb) {
        const int bl = wave * B_PER_WAVE + bb;       // local batch in slice
        float acc = 0.0f;
        for (int u = lane; u < nb; u += 64) {
            float A = 0.0f;
            #pragma unroll
            for (int i = 0; i < p; ++i) {
                const float xv = sxAll[bl * NQ + TAB.qb[Q][i]];  // LDS broadcast
                A += ((u >> i) & 1) ? xv : -xv;
            }
            float s, c;
            sincosf(A, &s, &c);
            acc += c * tabC[u] + s * tabS[u];
        }
        #pragma unroll
        for (int o = 32; o > 0; o >>= 1)
            acc += __shfl_down(acc, o, 64);
        if (lane == 0)
            out[(slice * SLICE_B + bl) * NQ + Q] = acc * (1.0f / (float)DIM);
    }
}

// -------- single fused kernel: grid = NQ x NSLICE, d_ws unused --------
__global__ __launch_bounds__(TB, 4)
void fused_kernel(const float* __restrict__ x, const float* __restrict__ params,
                  float* __restrict__ out)
{
    __shared__ float2 w[NGATES];                 // e^{i theta} per relevant gate
    __shared__ float  binC[NREP << MAXP];
    __shared__ float  binS[NREP << MAXP];
    __shared__ float  tabC[1 << MAXP];
    __shared__ float  tabS[1 << MAXP];
    __shared__ float  sxAll[SLICE_B * NQ];       // this slice's x rows

    const int q     = blockIdx.x % NQ;
    const int slice = blockIdx.x / NQ;
    const int t     = threadIdx.x;
    const int ng    = TAB.ng[q];

    if (t < ng) {
        const float th = params[(int)TAB.gidx[q][t]];
        float s, c; sincosf(th, &s, &c);
        w[t] = make_float2(c, s);
    }
    for (int i = t; i < (NREP << MAXP); i += TB) { binC[i] = 0.0f; binS[i] = 0.0f; }
    for (int i = t; i < SLICE_B * NQ; i += TB)   sxAll[i] = x[slice * (SLICE_B * NQ) + i];
    __syncthreads();

    switch (q) {
        case 0:  run_q<0 >(w, binC, binS, tabC, tabS, sxAll, out, slice, t); break;
        case 1:  run_q<1 >(w, binC, binS, tabC, tabS, sxAll, out, slice, t); break;
        case 2:  run_q<2 >(w, binC, binS, tabC, tabS, sxAll, out, slice, t); break;
        case 3:  run_q<3 >(w, binC, binS, tabC, tabS, sxAll, out, slice, t); break;
        case 4:  run_q<4 >(w, binC, binS, tabC, tabS, sxAll, out, slice, t); break;
        case 5:  run_q<5 >(w, binC, binS, tabC, tabS, sxAll, out, slice, t); break;
        case 6:  run_q<6 >(w, binC, binS, tabC, tabS, sxAll, out, slice, t); break;
        case 7:  run_q<7 >(w, binC, binS, tabC, tabS, sxAll, out, slice, t); break;
        case 8:  run_q<8 >(w, binC, binS, tabC, tabS, sxAll, out, slice, t); break;
        case 9:  run_q<9 >(w, binC, binS, tabC, tabS, sxAll, out, slice, t); break;
        case 10: run_q<10>(w, binC, binS, tabC, tabS, sxAll, out, slice, t); break;
        case 11: run_q<11>(w, binC, binS, tabC, tabS, sxAll, out, slice, t); break;
        case 12: run_q<12>(w, binC, binS, tabC, tabS, sxAll, out, slice, t); break;
        case 13: run_q<13>(w, binC, binS, tabC, tabS, sxAll, out, slice, t); break;
    }
}

extern "C" void kernel_launch(void* const* d_in, const int* in_sizes, int n_in,
                              void* d_out, int out_size, void* d_ws, size_t ws_size,
                              hipStream_t stream) {
    const float* x      = (const float*)d_in[0];   // (512, 14) float32
    const float* params = (const float*)d_in[1];   // (6, 1, 14) float32
    float* out          = (float*)d_out;           // (512, 14) float32
    (void)d_ws; (void)ws_size;                     // workspace intentionally unused

    fused_kernel<<<NQ * NSLICE, TB, 0, stream>>>(x, params, out);
}

// Round 2
// 61.570 us; speedup vs baseline: 1.1100x; 1.0441x over previous
//
#include <hip/hip_runtime.h>
#include <math.h>

// 14-qubit, 6-layer RX+CNOT-ring circuit, batch 512 — fully collapsed form.
//
// Verified chain (R3/R4/R7/R9/R10/R11 passed end-to-end):
//   out[b][q] = 2^-14 * sum_u [ cos(A_u) C^q_u + sin(A_u) S^q_u ]
//   C^q_u + i S^q_u = sum_{k: pext(k,r_q)=u} e^{i DTheta_k}
//   DTheta_k = sum_{g: <r_q,m_g> odd} (-1)^{popc(k&m_g)} theta_g
//
// R13 (passed, 64.3 us): single fused kernel, per-block LDS table rebuild,
// grid = 14 q x 16 slices, d_ws unused. Measured window = 39.4 us harness
// ws-poison fill + ~13 us fixed dispatch overhead + this kernel.
//
// R14: shave the kernel's VALU budget without touching the verified
// t/kk enumeration or bin structure:
//  (a) WHT last stage fused into the kk-sum: sum over a stage-s=8 pair is
//      A*B + A*conj(B) = A * 2Re(B), so
//      sum_kk B[kk] = 2 * sum_{h<8} B[h] * Bx[h|8]
//      -> 18 ops replace 64 (stage 4) + 30 (sum); upper-half stage-s=4
//      butterflies then only need real outputs (-16 more ops).
//      Mathematically identical; only FP summation order changes.
//  (b) __sincosf in phase B only (error bound: sum_u |tab_u| <= 16384,
//      fast-sincos err ~2e-6 -> out err <= 2e-6 after 1/DIM). w-prep keeps
//      precise sincosf (propagates through 42-gate products).
//  (c) lane-fixed low-6-bit part of A hoisted out of the u-loop; merged
//      table packed as float2 (one ds_read_b64 per term).
// SESSION RULE intact: each out[b][q] written by exactly one wave of one block.

#define NQ 14
#define DIM 16384
#define NLAYERS 6
#define NGATES (NLAYERS * NQ)   // 84
#define BATCH 512
#define TB 1024                 // threads per block
#define NREP 16                 // bin replicas, one per wave
#define NSLICE 16               // batch slices
#define SLICE_B (BATCH / NSLICE)        // 32 batches per block
#define B_PER_WAVE (SLICE_B * 64 / TB)  // 2 batches per wave

constexpr int cpopc(unsigned v) { int c = 0; while (v) { c += (int)(v & 1u); v >>= 1; } return c; }

constexpr unsigned cpext(unsigned v, unsigned m) {
    // extract bits of v at set positions of m, LSB-first
    unsigned r = 0; int b = 0;
    for (int pos = 0; pos < 16; ++pos)
        if ((m >> pos) & 1u) { r |= ((v >> pos) & 1u) << b; ++b; }
    return r;
}

struct Tabs {
    unsigned short m[NGATES];        // gate masks (k-bit-position space)
    unsigned short r[NQ];            // readout lag masks
    int p[NQ];                       // popc(r[q])
    int off[NQ + 1];                 // bin-table offsets (prefix sums of 2^p)
    unsigned char qb[NQ][NQ];        // qubit index per set bit of r (LSB-first)
    int ng[NQ];                      // # gates with odd overlap vs r[q]
    unsigned short gmask[NQ][NGATES];
    unsigned char  gidx[NQ][NGATES];
};

constexpr Tabs gen_tabs() {
    Tabs T{};
    unsigned short C[NQ] = {}, R[NQ] = {};
    for (int q = 0; q < NQ; ++q) { C[q] = (unsigned short)(1u << (NQ - 1 - q)); R[q] = C[q]; }
    for (int l = 0; l < NLAYERS; ++l) {
        for (int q = 0; q < NQ; ++q) T.m[l * NQ + q] = C[q];
        for (int g = 0; g < NQ; ++g) {           // sequential — matches all passing rounds
            int t = (g + 1) % NQ;
            C[g] ^= C[t];
            R[t] ^= R[g];
        }
    }
    for (int q = 0; q < NQ; ++q) T.r[q] = R[q];
    for (int q = 0; q < NQ; ++q) {
        int cnt = 0;
        for (int pos = 0; pos < NQ; ++pos)
            if ((R[q] >> pos) & 1u) { T.qb[q][cnt] = (unsigned char)(NQ - 1 - pos); ++cnt; }
        T.p[q] = cnt;
    }
    T.off[0] = 0;
    for (int q = 0; q < NQ; ++q) T.off[q + 1] = T.off[q] + (1 << T.p[q]);
    for (int q = 0; q < NQ; ++q) {
        int n = 0;
        for (int g = 0; g < NGATES; ++g) {
            if (cpopc((unsigned)(T.m[g] & R[q])) & 1) {
                T.gmask[q][n] = T.m[g];
                T.gidx[q][n]  = (unsigned char)g;
                ++n;
            }
        }
        T.ng[q] = n;
    }
    return T;
}
constexpr Tabs TAB = gen_tabs();

constexpr int calc_maxp() { int m = 0; for (int q = 0; q < NQ; ++q) if (TAB.p[q] > m) m = TAB.p[q]; return m; }
constexpr int calc_minp() { int m = 99; for (int q = 0; q < NQ; ++q) if (TAB.p[q] < m) m = TAB.p[q]; return m; }
constexpr int MAXP  = calc_maxp();
constexpr int MINP  = calc_minp();
constexpr int TOTAL = TAB.off[NQ];
static_assert(MAXP <= 8, "u = t & (2^p-1) needs p <= 10; replicas sized for p <= 8");
static_assert(MINP >= 1, "r mask must be nonzero");

// ---- recursive gate product: literal masks, register buckets only ----
template<int Q, int I>
__device__ __forceinline__ void gates(const float2* __restrict__ w, int t,
                                      float (&Bx)[16], float (&By)[16])
{
    if constexpr (I < TAB.ng[Q]) {
        constexpr unsigned r  = TAB.r[Q];
        constexpr unsigned nr = (~r) & 0x3FFFu;
        constexpr int      p  = TAB.p[Q];
        constexpr unsigned mg = TAB.gmask[Q][I];
        constexpr unsigned Ag = cpext(mg, r);                         // p bits
        constexpr unsigned Bg = cpext(mg, nr);                        // 14-p bits
        constexpr unsigned Mg = Ag | ((Bg & ((1u << (10 - p)) - 1u)) << p); // 10-bit
        constexpr unsigned Hg = (Bg >> (10 - p)) & 15u;               // 4-bit class
        const float2 wv = w[I];                       // ds_read_b64 broadcast
        const float si = (__popc((unsigned)t & Mg) & 1) ? -wv.y : wv.y;
        const float c  = wv.x;
        const float nx = Bx[Hg] * c - By[Hg] * si;
        const float ny = Bx[Hg] * si + By[Hg] * c;
        Bx[Hg] = nx; By[Hg] = ny;
        gates<Q, I + 1>(w, t, Bx, By);
    }
}

template<int Q>
__device__ __forceinline__ void build_q(const float2* __restrict__ w,
                                        float* __restrict__ binC,
                                        float* __restrict__ binS, int t)
{
    constexpr int      p       = TAB.p[Q];
    constexpr unsigned lowmask = (1u << p) - 1u;

    // phase 1: 16 complex buckets B[h] = e^{i P[h]} (t-part signs)
    float Bx[16], By[16];
    #pragma unroll
    for (int h = 0; h < 16; ++h) { Bx[h] = 1.0f; By[h] = 0.0f; }
    gates<Q, 0>(w, t, Bx, By);

    // phase 2: product-WHT (R10-verified), stages s=1,2 full
    #pragma unroll
    for (int s = 1; s < 4; s <<= 1) {
        #pragma unroll
        for (int h = 0; h < 16; ++h) {
            if (!(h & s)) {
                const int h1 = h | s;
                const float p1 = Bx[h] * Bx[h1], p2 = By[h] * By[h1];
                const float p3 = Bx[h] * By[h1], p4 = By[h] * Bx[h1];
                Bx[h]  = p1 - p2;  By[h]  = p3 + p4;   // A*B
                Bx[h1] = p1 + p2;  By[h1] = p4 - p3;   // A*conj(B)
            }
        }
    }
    // stage s=4: lower quads full; upper quads real-only (imag dead after fusion)
    #pragma unroll
    for (int h = 0; h < 4; ++h) {
        const int h1 = h | 4;
        const float p1 = Bx[h] * Bx[h1], p2 = By[h] * By[h1];
        const float p3 = Bx[h] * By[h1], p4 = By[h] * Bx[h1];
        Bx[h]  = p1 - p2;  By[h]  = p3 + p4;
        Bx[h1] = p1 + p2;  By[h1] = p4 - p3;
    }
    #pragma unroll
    for (int h = 8; h < 12; ++h) {
        const int h1 = h | 4;
        const float p1 = Bx[h] * Bx[h1], p2 = By[h] * By[h1];
        Bx[h]  = p1 - p2;               // Re(A*B)
        Bx[h1] = p1 + p2;               // Re(A*conj(B))
    }

    // fused stage s=8 + phase 3: sum_kk B[kk] = 2 * sum_{h<8} B[h] * Re(B[h|8])
    float fx = 0.0f, fy = 0.0f;
    #pragma unroll
    for (int h = 0; h < 8; ++h) {
        fx = fmaf(Bx[h | 8], Bx[h], fx);
        fy = fmaf(Bx[h | 8], By[h], fy);
    }
    fx *= 2.0f; fy *= 2.0f;

    const unsigned u   = (unsigned)t & lowmask;
    const int      rep = t >> 6;                 // per-wave replica
    float* bc = binC + (rep << MAXP);
    float* bs = binS + (rep << MAXP);

    if constexpr (p >= 6) {
        // lanes of a wave have distinct u; waves separated by replicas:
        // one plain store pair per thread, no shuffles, no atomics.
        bc[u] = fx;
        bs[u] = fy;
    } else {
        // group mates differ in lane bits p..5: short shuffle tree, lead writes
        constexpr unsigned dm = 63u & ~lowmask;
        #pragma unroll
        for (int bb = p; bb < 6; ++bb) {
            fx += __shfl_xor(fx, 1 << bb, 64);
            fy += __shfl_xor(fy, 1 << bb, 64);
        }
        if (((unsigned)t & dm) == 0u) {
            bc[u] = fx;
            bs[u] = fy;
        }
    }
}

// ---- fused per-block pipeline: build q-table in LDS, consume for 32 batches ----
template<int Q>
__device__ __forceinline__ void run_q(const float2* __restrict__ w,
                                      float* __restrict__ binC,
                                      float* __restrict__ binS,
                                      float2* __restrict__ tab2,
                                      const float* __restrict__ sxAll,
                                      float* __restrict__ out,
                                      int slice, int t)
{
    build_q<Q>(w, binC, binS, t);
    __syncthreads();

    // merge replicas into final LDS table (same fixed order as R12/R13)
    constexpr int p  = TAB.p[Q];
    constexpr int nb = 1 << p;
    for (int i = t; i < nb; i += TB) {
        float sc = 0.0f, ss = 0.0f;
        #pragma unroll
        for (int rp = 0; rp < NREP; ++rp) {
            sc += binC[(rp << MAXP) + i];
            ss += binS[(rp << MAXP) + i];
        }
        tab2[i] = make_float2(sc, ss);
    }
    __syncthreads();

    // phase B: each wave owns B_PER_WAVE batches; reduction stays in-wave.
    const int wave = t >> 6;
    const int lane = t & 63;
    #pragma unroll
    for (int bb = 0; bb < B_PER_WAVE; ++bb) {
        const int bl = wave * B_PER_WAVE + bb;       // local batch in slice
        const float* xr = sxAll + bl * NQ;
        float xv[p];
        #pragma unroll
        for (int i = 0; i < p; ++i) xv[i] = xr[TAB.qb[Q][i]];  // LDS broadcast

        float acc = 0.0f;
        if constexpr (p >= 6) {
            // u = lane + (j<<6): low-6-bit contribution to A is lane-fixed
            float A_low = 0.0f;
            #pragma unroll
            for (int i = 0; i < 6; ++i) A_low += ((lane >> i) & 1) ? xv[i] : -xv[i];
            constexpr int HI = 1 << (p - 6);
            #pragma unroll
            for (int j = 0; j < HI; ++j) {
                float A = A_low;
                #pragma unroll
                for (int i = 6; i < p; ++i) A += ((j >> (i - 6)) & 1) ? xv[i] : -xv[i];
                const int u = lane + (j << 6);
                float s, c;
                __sincosf(A, &s, &c);
                const float2 tv = tab2[u];
                acc = fmaf(c, tv.x, fmaf(s, tv.y, acc));
            }
        } else {
            if (lane < nb) {
                float A = 0.0f;
                #pragma unroll
                for (int i = 0; i < p; ++i) A += ((lane >> i) & 1) ? xv[i] : -xv[i];
                float s, c;
                __sincosf(A, &s, &c);
                const float2 tv = tab2[lane];
                acc = fmaf(c, tv.x, fmaf(s, tv.y, acc));
            }
        }

        #pragma unroll
        for (int o = 32; o > 0; o >>= 1)
            acc += __shfl_down(acc, o, 64);
        if (lane == 0)
            out[(slice * SLICE_B + bl) * NQ + Q] = acc * (1.0f / (float)DIM);
    }
}

// -------- single fused kernel: grid = NQ x NSLICE, d_ws unused --------
__global__ __launch_bounds__(TB, 4)
void fused_kernel(const float* __restrict__ x, const float* __restrict__ params,
                  float* __restrict__ out)
{
    __shared__ float2 w[NGATES];                 // e^{i theta} per relevant gate
    __shared__ float  binC[NREP << MAXP];
    __shared__ float  binS[NREP << MAXP];
    __shared__ float2 tab2[1 << MAXP];
    __shared__ float  sxAll[SLICE_B * NQ];       // this slice's x rows

    const int q     = blockIdx.x % NQ;
    const int slice = blockIdx.x / NQ;
    const int t     = threadIdx.x;
    const int ng    = TAB.ng[q];

    if (t < ng) {
        const float th = params[(int)TAB.gidx[q][t]];
        float s, c; sincosf(th, &s, &c);         // precise: feeds 42-gate products
        w[t] = make_float2(c, s);
    }
    for (int i = t; i < (NREP << MAXP); i += TB) { binC[i] = 0.0f; binS[i] = 0.0f; }
    for (int i = t; i < SLICE_B * NQ; i += TB)   sxAll[i] = x[slice * (SLICE_B * NQ) + i];
    __syncthreads();

    switch (q) {
        case 0:  run_q<0 >(w, binC, binS, tab2, sxAll, out, slice, t); break;
        case 1:  run_q<1 >(w, binC, binS, tab2, sxAll, out, slice, t); break;
        case 2:  run_q<2 >(w, binC, binS, tab2, sxAll, out, slice, t); break;
        case 3:  run_q<3 >(w, binC, binS, tab2, sxAll, out, slice, t); break;
        case 4:  run_q<4 >(w, binC, binS, tab2, sxAll, out, slice, t); break;
        case 5:  run_q<5 >(w, binC, binS, tab2, sxAll, out, slice, t); break;
        case 6:  run_q<6 >(w, binC, binS, tab2, sxAll, out, slice, t); break;
        case 7:  run_q<7 >(w, binC, binS, tab2, sxAll, out, slice, t); break;
        case 8:  run_q<8 >(w, binC, binS, tab2, sxAll, out, slice, t); break;
        case 9:  run_q<9 >(w, binC, binS, tab2, sxAll, out, slice, t); break;
        case 10: run_q<10>(w, binC, binS, tab2, sxAll, out, slice, t); break;
        case 11: run_q<11>(w, binC, binS, tab2, sxAll, out, slice, t); break;
        case 12: run_q<12>(w, binC, binS, tab2, sxAll, out, slice, t); break;
        case 13: run_q<13>(w, binC, binS, tab2, sxAll, out, slice, t); break;
    }
}

extern "C" void kernel_launch(void* const* d_in, const int* in_sizes, int n_in,
                              void* d_out, int out_size, void* d_ws, size_t ws_size,
                              hipStream_t stream) {
    const float* x      = (const float*)d_in[0];   // (512, 14) float32
    const float* params = (const float*)d_in[1];   // (6, 1, 14) float32
    float* out          = (float*)d_out;           // (512, 14) float32
    (void)d_ws; (void)ws_size;                     // workspace intentionally unused

    fused_kernel<<<NQ * NSLICE, TB, 0, stream>>>(x, params, out);
}

// Round 3
// 57.291 us; speedup vs baseline: 1.1929x; 1.0747x over previous
//
#include <hip/hip_runtime.h>
#include <math.h>

// 14-qubit, 6-layer RX+CNOT-ring circuit, batch 512 — fully collapsed form.
//
// Verified chain (R3/R4/R7/R9/R10/R11 passed end-to-end):
//   out[b][q] = 2^-14 * sum_u [ cos(A_u) C^q_u + sin(A_u) S^q_u ]
//   C^q_u + i S^q_u = sum_{k: pext(k,r_q)=u} e^{i DTheta_k}
//   DTheta_k = sum_{g: <r_q,m_g> odd} (-1)^{popc(k&m_g)} theta_g
//
// R13 (64.3 us): single fused kernel, per-block LDS table rebuild, 224 blocks.
// R14 (61.6 us): WHT last stage fused into kk-sum, __sincosf phase B, packed tab.
// Window model (confirmed twice): 39.4 us harness ws-poison fill + ~13 us fixed
// dispatch overhead + this kernel (~6 us). Kernel cuts show up 1:1 in dur_us.
//
// R15: angle-domain build. Every bucket is a UNIT phasor, and the verified
// product-WHT butterfly (A*B, A*conj(B)) is exactly (a+b, a-b) on angles:
//  (a) phase 1 accumulates 16 scalar angle sums P[h] += sigma_g(t)*theta_g
//      (6 VALU/gate vs 9 — no complex rotation); theta read via uniform
//      scalar loads (constexpr gidx) — w[] LDS array and its sincos DELETED.
//  (b) phase 2 WHT = add/sub butterflies on 16 scalars (48 ops vs 176).
//  (c) R14-verified fused last stage, angle form:
//      sum_kk B[kk] = 2 * sum_{h<8} cos(P[h|8]) * e^{i P[h]}
//      -> 8 __sincosf + 8 __cosf. |Phi| <= 42*2pi ~ 42 rev < v_sin's 256-rev range.
//  (d) writer-indexed replica merge: rep writes only bins with
//      i>>6 == rep mod 2^(p-6); summing only actual writers (ascending rep,
//      bitwise-identical result) makes the 32 KB bin zero-init DEAD — deleted.
//  (e) phase B: one u-loop for the wave's 2 batches (shared tab2 reads).
// SESSION RULE intact: each out[b][q] written by exactly one wave of one block.

#define NQ 14
#define DIM 16384
#define NLAYERS 6
#define NGATES (NLAYERS * NQ)   // 84
#define BATCH 512
#define TB 1024                 // threads per block
#define NREP 16                 // bin replicas, one per wave
#define NSLICE 16               // batch slices
#define SLICE_B (BATCH / NSLICE)        // 32 batches per block
#define B_PER_WAVE (SLICE_B * 64 / TB)  // 2 batches per wave
static_assert(B_PER_WAVE == 2, "phase B hand-unrolled for 2 batches/wave");

constexpr int cpopc(unsigned v) { int c = 0; while (v) { c += (int)(v & 1u); v >>= 1; } return c; }

constexpr unsigned cpext(unsigned v, unsigned m) {
    // extract bits of v at set positions of m, LSB-first
    unsigned r = 0; int b = 0;
    for (int pos = 0; pos < 16; ++pos)
        if ((m >> pos) & 1u) { r |= ((v >> pos) & 1u) << b; ++b; }
    return r;
}

struct Tabs {
    unsigned short m[NGATES];        // gate masks (k-bit-position space)
    unsigned short r[NQ];            // readout lag masks
    int p[NQ];                       // popc(r[q])
    int off[NQ + 1];                 // bin-table offsets (prefix sums of 2^p)
    unsigned char qb[NQ][NQ];        // qubit index per set bit of r (LSB-first)
    int ng[NQ];                      // # gates with odd overlap vs r[q]
    unsigned short gmask[NQ][NGATES];
    unsigned char  gidx[NQ][NGATES];
};

constexpr Tabs gen_tabs() {
    Tabs T{};
    unsigned short C[NQ] = {}, R[NQ] = {};
    for (int q = 0; q < NQ; ++q) { C[q] = (unsigned short)(1u << (NQ - 1 - q)); R[q] = C[q]; }
    for (int l = 0; l < NLAYERS; ++l) {
        for (int q = 0; q < NQ; ++q) T.m[l * NQ + q] = C[q];
        for (int g = 0; g < NQ; ++g) {           // sequential — matches all passing rounds
            int t = (g + 1) % NQ;
            C[g] ^= C[t];
            R[t] ^= R[g];
        }
    }
    for (int q = 0; q < NQ; ++q) T.r[q] = R[q];
    for (int q = 0; q < NQ; ++q) {
        int cnt = 0;
        for (int pos = 0; pos < NQ; ++pos)
            if ((R[q] >> pos) & 1u) { T.qb[q][cnt] = (unsigned char)(NQ - 1 - pos); ++cnt; }
        T.p[q] = cnt;
    }
    T.off[0] = 0;
    for (int q = 0; q < NQ; ++q) T.off[q + 1] = T.off[q] + (1 << T.p[q]);
    for (int q = 0; q < NQ; ++q) {
        int n = 0;
        for (int g = 0; g < NGATES; ++g) {
            if (cpopc((unsigned)(T.m[g] & R[q])) & 1) {
                T.gmask[q][n] = T.m[g];
                T.gidx[q][n]  = (unsigned char)g;
                ++n;
            }
        }
        T.ng[q] = n;
    }
    return T;
}
constexpr Tabs TAB = gen_tabs();

constexpr int calc_maxp() { int m = 0; for (int q = 0; q < NQ; ++q) if (TAB.p[q] > m) m = TAB.p[q]; return m; }
constexpr int calc_minp() { int m = 99; for (int q = 0; q < NQ; ++q) if (TAB.p[q] < m) m = TAB.p[q]; return m; }
constexpr int MAXP  = calc_maxp();
constexpr int MINP  = calc_minp();
constexpr int TOTAL = TAB.off[NQ];
static_assert(MAXP <= 8, "u = t & (2^p-1) needs p <= 10; replicas sized for p <= 8");
static_assert(MINP >= 1, "r mask must be nonzero");

// ---- recursive gate ANGLE accumulation: literal masks, register buckets ----
template<int Q, int I>
__device__ __forceinline__ void gates(const float* __restrict__ params, int t,
                                      float (&P)[16])
{
    if constexpr (I < TAB.ng[Q]) {
        constexpr unsigned r  = TAB.r[Q];
        constexpr unsigned nr = (~r) & 0x3FFFu;
        constexpr int      p  = TAB.p[Q];
        constexpr unsigned mg = TAB.gmask[Q][I];
        constexpr unsigned Ag = cpext(mg, r);                         // p bits
        constexpr unsigned Bg = cpext(mg, nr);                        // 14-p bits
        constexpr unsigned Mg = Ag | ((Bg & ((1u << (10 - p)) - 1u)) << p); // 10-bit
        constexpr unsigned Hg = (Bg >> (10 - p)) & 15u;               // 4-bit class
        const float th = params[(int)TAB.gidx[Q][I]];  // uniform addr -> s_load broadcast
        P[Hg] += (__popc((unsigned)t & Mg) & 1) ? -th : th;
        gates<Q, I + 1>(params, t, P);
    }
}

template<int Q>
__device__ __forceinline__ void build_q(const float* __restrict__ params,
                                        float* __restrict__ binC,
                                        float* __restrict__ binS, int t)
{
    constexpr int      p       = TAB.p[Q];
    constexpr unsigned lowmask = (1u << p) - 1u;

    // phase 1: 16 angle sums P[h] = sum_{g in class h} sigma_g(t) theta_g
    float P[16];
    #pragma unroll
    for (int h = 0; h < 16; ++h) P[h] = 0.0f;
    gates<Q, 0>(params, t, P);

    // phase 2: WHT on ANGLES — isomorph of the R10-verified product-WHT:
    // (A*B, A*conj(B)) == angles (a+b, a-b). Stages s=1,2,4.
    #pragma unroll
    for (int s = 1; s < 8; s <<= 1) {
        #pragma unroll
        for (int h = 0; h < 16; ++h) {
            if (!(h & s)) {
                const int h1 = h | s;
                const float a = P[h], b = P[h1];
                P[h]  = a + b;
                P[h1] = a - b;
            }
        }
    }

    // fused stage s=8 + kk-sum (R14-verified identity, angle form):
    // sum_kk B[kk] = 2 * sum_{h<8} cos(P[h|8]) * e^{i P[h]}
    float fx = 0.0f, fy = 0.0f;
    #pragma unroll
    for (int h = 0; h < 8; ++h) {
        float sa, ca;
        __sincosf(P[h], &sa, &ca);
        const float cb = __cosf(P[h | 8]);
        fx = fmaf(cb, ca, fx);
        fy = fmaf(cb, sa, fy);
    }
    fx *= 2.0f; fy *= 2.0f;

    const unsigned u   = (unsigned)t & lowmask;
    const int      rep = t >> 6;                 // per-wave replica
    float* bc = binC + (rep << MAXP);
    float* bs = binS + (rep << MAXP);

    if constexpr (p >= 6) {
        // lanes of a wave have distinct u; waves separated by replicas:
        // one plain store pair per thread, no shuffles, no atomics.
        bc[u] = fx;
        bs[u] = fy;
    } else {
        // group mates differ in lane bits p..5: short shuffle tree, lead writes
        constexpr unsigned dm = 63u & ~lowmask;
        #pragma unroll
        for (int bb = p; bb < 6; ++bb) {
            fx += __shfl_xor(fx, 1 << bb, 64);
            fy += __shfl_xor(fy, 1 << bb, 64);
        }
        if (((unsigned)t & dm) == 0u) {
            bc[u] = fx;
            bs[u] = fy;
        }
    }
}

// ---- fused per-block pipeline: build q-table in LDS, consume for 32 batches ----
template<int Q>
__device__ __forceinline__ void run_q(const float* __restrict__ params,
                                      float* __restrict__ binC,
                                      float* __restrict__ binS,
                                      float2* __restrict__ tab2,
                                      const float* __restrict__ sxAll,
                                      float* __restrict__ out,
                                      int slice, int t)
{
    build_q<Q>(params, binC, binS, t);
    __syncthreads();

    // merge replicas. Writer analysis: rep writes u = (rep mod 2^(p-6))*64+lane,
    // so bin i's writers are rp = (i>>6) + c*2^(p-6) — read ONLY those, in
    // ascending rp (same nonzero order as full 0..15 sweep -> bitwise identical).
    constexpr int p  = TAB.p[Q];
    constexpr int nb = 1 << p;
    if constexpr (p >= 6) {
        constexpr int STRIDE = 1 << (p - 6);
        constexpr int NW     = NREP / STRIDE;      // writers per bin
        for (int i = t; i < nb; i += TB) {
            const int r0 = i >> 6;
            float sc = 0.0f, ss = 0.0f;
            #pragma unroll
            for (int c = 0; c < NW; ++c) {
                const int rp = r0 + c * STRIDE;
                sc += binC[(rp << MAXP) + i];
                ss += binS[(rp << MAXP) + i];
            }
            tab2[i] = make_float2(sc, ss);
        }
    } else {
        // p < 6: every rep's lead lanes wrote all 2^p bins — full sweep
        for (int i = t; i < nb; i += TB) {
            float sc = 0.0f, ss = 0.0f;
            #pragma unroll
            for (int rp = 0; rp < NREP; ++rp) {
                sc += binC[(rp << MAXP) + i];
                ss += binS[(rp << MAXP) + i];
            }
            tab2[i] = make_float2(sc, ss);
        }
    }
    __syncthreads();

    // phase B: each wave owns 2 batches, one shared u-loop; reduction in-wave.
    const int wave = t >> 6;
    const int lane = t & 63;
    const int bl0  = wave * B_PER_WAVE;
    const float* xr0 = sxAll + bl0 * NQ;
    const float* xr1 = xr0 + NQ;

    float acc0 = 0.0f, acc1 = 0.0f;
    if constexpr (p >= 6) {
        float xv0[p], xv1[p];
        #pragma unroll
        for (int i = 0; i < p; ++i) {
            xv0[i] = xr0[TAB.qb[Q][i]];            // LDS broadcast
            xv1[i] = xr1[TAB.qb[Q][i]];
        }
        // u = lane + (j<<6): low-6-bit contribution to A is lane-fixed
        float A0 = 0.0f, A1 = 0.0f;
        #pragma unroll
        for (int i = 0; i < 6; ++i) {
            const bool bset = (lane >> i) & 1;
            A0 += bset ? xv0[i] : -xv0[i];
            A1 += bset ? xv1[i] : -xv1[i];
        }
        constexpr int HI = 1 << (p - 6);
        #pragma unroll
        for (int j = 0; j < HI; ++j) {
            float Aj0 = A0, Aj1 = A1;
            #pragma unroll
            for (int i = 6; i < p; ++i) {
                const bool bset = (j >> (i - 6)) & 1;
                Aj0 += bset ? xv0[i] : -xv0[i];
                Aj1 += bset ? xv1[i] : -xv1[i];
            }
            const float2 tv = tab2[lane + (j << 6)];  // shared by both batches
            float s0, c0, s1, c1;
            __sincosf(Aj0, &s0, &c0);
            __sincosf(Aj1, &s1, &c1);
            acc0 = fmaf(c0, tv.x, fmaf(s0, tv.y, acc0));
            acc1 = fmaf(c1, tv.x, fmaf(s1, tv.y, acc1));
        }
    } else {
        if (lane < nb) {
            float A0 = 0.0f, A1 = 0.0f;
            #pragma unroll
            for (int i = 0; i < p; ++i) {
                const bool bset = (lane >> i) & 1;
                const float x0 = xr0[TAB.qb[Q][i]];
                const float x1 = xr1[TAB.qb[Q][i]];
                A0 += bset ? x0 : -x0;
                A1 += bset ? x1 : -x1;
            }
            const float2 tv = tab2[lane];
            float s0, c0, s1, c1;
            __sincosf(A0, &s0, &c0);
            __sincosf(A1, &s1, &c1);
            acc0 = fmaf(c0, tv.x, fmaf(s0, tv.y, acc0));
            acc1 = fmaf(c1, tv.x, fmaf(s1, tv.y, acc1));
        }
    }

    #pragma unroll
    for (int o = 32; o > 0; o >>= 1) {
        acc0 += __shfl_down(acc0, o, 64);
        acc1 += __shfl_down(acc1, o, 64);
    }
    if (lane == 0) {
        out[(slice * SLICE_B + bl0)     * NQ + Q] = acc0 * (1.0f / (float)DIM);
        out[(slice * SLICE_B + bl0 + 1) * NQ + Q] = acc1 * (1.0f / (float)DIM);
    }
}

// -------- single fused kernel: grid = NQ x NSLICE, d_ws unused --------
__global__ __launch_bounds__(TB, 4)
void fused_kernel(const float* __restrict__ x, const float* __restrict__ params,
                  float* __restrict__ out)
{
    __shared__ float  binC[NREP << MAXP];
    __shared__ float  binS[NREP << MAXP];
    __shared__ float2 tab2[1 << MAXP];
    __shared__ float  sxAll[SLICE_B * NQ];       // this slice's x rows

    const int q     = blockIdx.x % NQ;
    const int slice = blockIdx.x / NQ;
    const int t     = threadIdx.x;

    // No bin zero-init needed: the writer-indexed merge reads only written
    // entries. sxAll writes are ordered before phase B by the two syncs in run_q.
    for (int i = t; i < SLICE_B * NQ; i += TB) sxAll[i] = x[slice * (SLICE_B * NQ) + i];

    switch (q) {
        case 0:  run_q<0 >(params, binC, binS, tab2, sxAll, out, slice, t); break;
        case 1:  run_q<1 >(params, binC, binS, tab2, sxAll, out, slice, t); break;
        case 2:  run_q<2 >(params, binC, binS, tab2, sxAll, out, slice, t); break;
        case 3:  run_q<3 >(params, binC, binS, tab2, sxAll, out, slice, t); break;
        case 4:  run_q<4 >(params, binC, binS, tab2, sxAll, out, slice, t); break;
        case 5:  run_q<5 >(params, binC, binS, tab2, sxAll, out, slice, t); break;
        case 6:  run_q<6 >(params, binC, binS, tab2, sxAll, out, slice, t); break;
        case 7:  run_q<7 >(params, binC, binS, tab2, sxAll, out, slice, t); break;
        case 8:  run_q<8 >(params, binC, binS, tab2, sxAll, out, slice, t); break;
        case 9:  run_q<9 >(params, binC, binS, tab2, sxAll, out, slice, t); break;
        case 10: run_q<10>(params, binC, binS, tab2, sxAll, out, slice, t); break;
        case 11: run_q<11>(params, binC, binS, tab2, sxAll, out, slice, t); break;
        case 12: run_q<12>(params, binC, binS, tab2, sxAll, out, slice, t); break;
        case 13: run_q<13>(params, binC, binS, tab2, sxAll, out, slice, t); break;
    }
}

extern "C" void kernel_launch(void* const* d_in, const int* in_sizes, int n_in,
                              void* d_out, int out_size, void* d_ws, size_t ws_size,
                              hipStream_t stream) {
    const float* x      = (const float*)d_in[0];   // (512, 14) float32
    const float* params = (const float*)d_in[1];   // (6, 1, 14) float32
    float* out          = (float*)d_out;           // (512, 14) float32
    (void)d_ws; (void)ws_size;                     // workspace intentionally unused

    fused_kernel<<<NQ * NSLICE, TB, 0, stream>>>(x, params, out);
}

// Round 5
// 56.467 us; speedup vs baseline: 1.2103x; 1.0146x over previous
//
#include <hip/hip_runtime.h>
#include <math.h>

// 14-qubit, 6-layer RX+CNOT-ring circuit, batch 512 — fully collapsed form.
//
// Verified chain (R3/R4/R7/R9/R10/R11 passed end-to-end):
//   out[b][q] = 2^-14 * sum_u [ cos(A_u) C^q_u + sin(A_u) S^q_u ]
//   C^q_u + i S^q_u = sum_{k: pext(k,r_q)=u} e^{i DTheta_k}
//   DTheta_k = sum_{g: <r_q,m_g> odd} (-1)^{popc(k&m_g)} theta_g
//
// R13 (64.3): single fused kernel, per-block LDS table rebuild, 224 blocks.
// R14 (61.6): WHT last stage fused into kk-sum, __sincosf phase B.
// R15 (57.3): angle-domain build (P[h] sums + add/sub WHT), w[] LDS deleted,
//             writer-indexed merge (zero-init deleted). Over-delivery showed
//             the kernel is partly LDS-PIPE bound.
// R16 (compile fail): constexpr step-limit blowout in gen_luts (remap_mask
//             re-evaluated in inner loop) + non-ICE ctrl arg to update_dpp.
//
// R17 = R16 with the two compile fixes:
//  (a) DPP wave reduction (row_shr 1/2/4/8 + row_bcast 15/31), ctrl as a
//      TEMPLATE parameter (ICE); store from lane 63. Replaces 12 LDS shuffle ops.
//  (b) x staged PRE-PERMUTED by qb[q], padded to 8 floats -> phase B xv loads
//      are 2 ds_read_b128 per batch; bins packed float2 (1 ds_write_b64).
//  (c) sign-LUTs built from a hoisted constexpr RMAP table + parity table
//      (~190k constexpr steps, under clang's limit). Signs bitwise-identical:
//      parity(t&Mg) = parity(lane&(Mg&63)) ^ parity(wid&(Mg>>6)).
//  (d) global x2 folded into the output scale (2/DIM = 2^-13, exact).
// SESSION RULE intact: each out[b][q] written by exactly one wave of one block.

#define NQ 14
#define DIM 16384
#define NLAYERS 6
#define NGATES (NLAYERS * NQ)   // 84
#define BATCH 512
#define TB 1024                 // threads per block
#define NREP 16                 // bin replicas, one per wave
#define NSLICE 16               // batch slices
#define SLICE_B (BATCH / NSLICE)        // 32 batches per block
#define B_PER_WAVE (SLICE_B * 64 / TB)  // 2 batches per wave
static_assert(B_PER_WAVE == 2, "phase B hand-unrolled for 2 batches/wave");

constexpr int cpopc(unsigned v) { int c = 0; while (v) { c += (int)(v & 1u); v >>= 1; } return c; }

constexpr unsigned cpext(unsigned v, unsigned m) {
    // extract bits of v at set positions of m, LSB-first
    unsigned r = 0; int b = 0;
    for (int pos = 0; pos < 16; ++pos)
        if ((m >> pos) & 1u) { r |= ((v >> pos) & 1u) << b; ++b; }
    return r;
}

struct Tabs {
    unsigned short m[NGATES];        // gate masks (k-bit-position space)
    unsigned short r[NQ];            // readout lag masks
    int p[NQ];                       // popc(r[q])
    int off[NQ + 1];                 // bin-table offsets (prefix sums of 2^p)
    unsigned char qb[NQ][NQ];        // qubit index per set bit of r (LSB-first)
    int ng[NQ];                      // # gates with odd overlap vs r[q]
    unsigned short gmask[NQ][NGATES];
    unsigned char  gidx[NQ][NGATES];
};

constexpr Tabs gen_tabs() {
    Tabs T{};
    unsigned short C[NQ] = {}, R[NQ] = {};
    for (int q = 0; q < NQ; ++q) { C[q] = (unsigned short)(1u << (NQ - 1 - q)); R[q] = C[q]; }
    for (int l = 0; l < NLAYERS; ++l) {
        for (int q = 0; q < NQ; ++q) T.m[l * NQ + q] = C[q];
        for (int g = 0; g < NQ; ++g) {           // sequential — matches all passing rounds
            int t = (g + 1) % NQ;
            C[g] ^= C[t];
            R[t] ^= R[g];
        }
    }
    for (int q = 0; q < NQ; ++q) T.r[q] = R[q];
    for (int q = 0; q < NQ; ++q) {
        int cnt = 0;
        for (int pos = 0; pos < NQ; ++pos)
            if ((R[q] >> pos) & 1u) { T.qb[q][cnt] = (unsigned char)(NQ - 1 - pos); ++cnt; }
        T.p[q] = cnt;
    }
    T.off[0] = 0;
    for (int q = 0; q < NQ; ++q) T.off[q + 1] = T.off[q] + (1 << T.p[q]);
    for (int q = 0; q < NQ; ++q) {
        int n = 0;
        for (int g = 0; g < NGATES; ++g) {
            if (cpopc((unsigned)(T.m[g] & R[q])) & 1) {
                T.gmask[q][n] = T.m[g];
                T.gidx[q][n]  = (unsigned char)g;
                ++n;
            }
        }
        T.ng[q] = n;
    }
    return T;
}
constexpr Tabs TAB = gen_tabs();

constexpr int calc_maxp() { int m = 0; for (int q = 0; q < NQ; ++q) if (TAB.p[q] > m) m = TAB.p[q]; return m; }
constexpr int calc_minp() { int m = 99; for (int q = 0; q < NQ; ++q) if (TAB.p[q] < m) m = TAB.p[q]; return m; }
constexpr int calc_maxng() { int m = 0; for (int q = 0; q < NQ; ++q) if (TAB.ng[q] > m) m = TAB.ng[q]; return m; }
constexpr int MAXP  = calc_maxp();
constexpr int MINP  = calc_minp();
constexpr int TOTAL = TAB.off[NQ];
static_assert(MAXP <= 8, "u = t & (2^p-1) needs p <= 10; replicas sized for p <= 8");
static_assert(MINP >= 1, "r mask must be nonzero");
static_assert(calc_maxng() <= 64, "sign vector packed in one uint64");

// ---- R17(c): compile-time sign LUTs, step-bounded construction --------------
// Remapped 10-bit mask Mg (identical construction to the gates<> recursion).
struct RMaps { unsigned m[NQ][NGATES]; };
constexpr RMaps gen_rmap() {
    RMaps M{};
    for (int q = 0; q < NQ; ++q) {
        const unsigned r  = TAB.r[q];
        const unsigned nr = (~r) & 0x3FFFu;
        const int      p  = TAB.p[q];
        for (int n = 0; n < TAB.ng[q]; ++n) {
            const unsigned mg = TAB.gmask[q][n];
            const unsigned Ag = cpext(mg, r);
            const unsigned Bg = cpext(mg, nr);
            M.m[q][n] = Ag | ((Bg & ((1u << (10 - p)) - 1u)) << p);
        }
    }
    return M;
}
constexpr RMaps RMAP = gen_rmap();

struct Par64 { unsigned char v[64]; };
constexpr Par64 gen_par64() {
    Par64 P{};
    for (int i = 0; i < 64; ++i) {
        unsigned x = (unsigned)i;
        x ^= x >> 4; x ^= x >> 2; x ^= x >> 1;
        P.v[i] = (unsigned char)(x & 1u);
    }
    return P;
}
constexpr Par64 PAR = gen_par64();

// parity(t & Mg) = parity(lane & (Mg&63)) ^ parity(wid & (Mg>>6)).
struct SignLuts {
    unsigned long long lane[NQ][64];
    unsigned long long wave[NQ][16];
};
constexpr SignLuts gen_luts() {
    SignLuts L{};
    for (int q = 0; q < NQ; ++q) {
        for (int ln = 0; ln < 64; ++ln) {
            unsigned long long v = 0;
            for (int n = 0; n < TAB.ng[q]; ++n)
                if (PAR.v[(unsigned)ln & (RMAP.m[q][n] & 63u)]) v |= 1ull << n;
            L.lane[q][ln] = v;
        }
        for (int wd = 0; wd < 16; ++wd) {
            unsigned long long v = 0;
            for (int n = 0; n < TAB.ng[q]; ++n)
                if (PAR.v[(unsigned)wd & (RMAP.m[q][n] >> 6)]) v |= 1ull << n;
            L.wave[q][wd] = v;
        }
    }
    return L;
}
constexpr SignLuts SLUT = gen_luts();

// ---- R17(a): DPP wave64 sum (ctrl as template ICE), total lands in lane 63 --
template<int CTRL>
__device__ __forceinline__ float dpp_add(float v) {
    const int s = __builtin_amdgcn_update_dpp(0, __float_as_int(v), CTRL, 0xf, 0xf, true);
    return v + __int_as_float(s);
}
__device__ __forceinline__ float wave64_sum(float v) {
    v = dpp_add<0x111>(v);   // row_shr:1
    v = dpp_add<0x112>(v);   // row_shr:2
    v = dpp_add<0x114>(v);   // row_shr:4
    v = dpp_add<0x118>(v);   // row_shr:8  -> lane15 of each row = row sum
    v = dpp_add<0x142>(v);   // row_bcast:15 (invalid lanes add 0, bound_ctrl)
    v = dpp_add<0x143>(v);   // row_bcast:31 -> lane63 = wave sum
    return v;
}

// ---- recursive gate ANGLE accumulation: LUT signs, register buckets ---------
template<int Q, int I>
__device__ __forceinline__ void gates(const float* __restrict__ params,
                                      unsigned svLo, unsigned svHi,
                                      float (&P)[16])
{
    if constexpr (I < TAB.ng[Q]) {
        constexpr unsigned r  = TAB.r[Q];
        constexpr unsigned nr = (~r) & 0x3FFFu;
        constexpr int      p  = TAB.p[Q];
        constexpr unsigned mg = TAB.gmask[Q][I];
        constexpr unsigned Bg = cpext(mg, nr);
        constexpr unsigned Hg = (Bg >> (10 - p)) & 15u;               // 4-bit class
        const float th = params[(int)TAB.gidx[Q][I]];  // uniform addr -> s_load
        const unsigned svh = (I < 32) ? svLo : svHi;
        const unsigned sgn = (svh << (31 - (I & 31))) & 0x80000000u;
        P[Hg] += __uint_as_float(__float_as_uint(th) ^ sgn);
        gates<Q, I + 1>(params, svLo, svHi, P);
    }
}

template<int Q>
__device__ __forceinline__ void build_q(const float* __restrict__ params,
                                        float2* __restrict__ bins2, int t)
{
    constexpr int      p       = TAB.p[Q];
    constexpr unsigned lowmask = (1u << p) - 1u;

    const int lane = t & 63;
    const int wid  = t >> 6;
    const unsigned long long sv = SLUT.lane[Q][lane] ^ SLUT.wave[Q][wid];
    const unsigned svLo = (unsigned)sv;
    const unsigned svHi = (unsigned)(sv >> 32);

    // phase 1: 16 angle sums P[h] = sum_{g in class h} sigma_g(t) theta_g
    float P[16];
    #pragma unroll
    for (int h = 0; h < 16; ++h) P[h] = 0.0f;
    gates<Q, 0>(params, svLo, svHi, P);

    // phase 2: WHT on ANGLES — isomorph of the R10-verified product-WHT:
    // (A*B, A*conj(B)) == angles (a+b, a-b). Stages s=1,2,4.
    #pragma unroll
    for (int s = 1; s < 8; s <<= 1) {
        #pragma unroll
        for (int h = 0; h < 16; ++h) {
            if (!(h & s)) {
                const int h1 = h | s;
                const float a = P[h], b = P[h1];
                P[h]  = a + b;
                P[h1] = a - b;
            }
        }
    }

    // fused stage s=8 + kk-sum (R14-verified identity, angle form):
    // sum_kk B[kk] = 2 * sum_{h<8} cos(P[h|8]) * e^{i P[h]}
    // (the x2 is folded into the output scale — exact)
    float fx = 0.0f, fy = 0.0f;
    #pragma unroll
    for (int h = 0; h < 8; ++h) {
        float sa, ca;
        __sincosf(P[h], &sa, &ca);
        const float cb = __cosf(P[h | 8]);
        fx = fmaf(cb, ca, fx);
        fy = fmaf(cb, sa, fy);
    }

    const unsigned u = (unsigned)t & lowmask;
    float2* bp = bins2 + (wid << MAXP);          // per-wave replica

    if constexpr (p >= 6) {
        // lanes of a wave have distinct u; waves separated by replicas:
        // one ds_write_b64 per thread, no shuffles, no atomics.
        bp[u] = make_float2(fx, fy);
    } else {
        // group mates differ in lane bits p..5: short shuffle tree, lead writes
        constexpr unsigned dm = 63u & ~lowmask;
        #pragma unroll
        for (int bb = p; bb < 6; ++bb) {
            fx += __shfl_xor(fx, 1 << bb, 64);
            fy += __shfl_xor(fy, 1 << bb, 64);
        }
        if (((unsigned)t & dm) == 0u) {
            bp[u] = make_float2(fx, fy);
        }
    }
}

// ---- fused per-block pipeline: build q-table in LDS, consume for 32 batches ----
template<int Q>
__device__ __forceinline__ void run_q(const float* __restrict__ params,
                                      float2* __restrict__ bins2,
                                      float2* __restrict__ tab2,
                                      const float4* __restrict__ sxPerm4,
                                      float* __restrict__ out,
                                      int slice, int t)
{
    build_q<Q>(params, bins2, t);
    __syncthreads();

    // merge replicas. Writer analysis: rep writes u = (rep mod 2^(p-6))*64+lane,
    // so bin i's writers are rp = (i>>6) + c*2^(p-6) — read ONLY those, in
    // ascending rp (same nonzero order as full 0..15 sweep -> bitwise identical).
    constexpr int p  = TAB.p[Q];
    constexpr int nb = 1 << p;
    if constexpr (p >= 6) {
        constexpr int STRIDE = 1 << (p - 6);
        constexpr int NW     = NREP / STRIDE;      // writers per bin
        for (int i = t; i < nb; i += TB) {
            const int r0 = i >> 6;
            float sc = 0.0f, ss = 0.0f;
            #pragma unroll
            for (int c = 0; c < NW; ++c) {
                const float2 v = bins2[((r0 + c * STRIDE) << MAXP) + i];
                sc += v.x; ss += v.y;
            }
            tab2[i] = make_float2(sc, ss);
        }
    } else {
        // p < 6: every rep's lead lanes wrote all 2^p bins — full sweep
        for (int i = t; i < nb; i += TB) {
            float sc = 0.0f, ss = 0.0f;
            #pragma unroll
            for (int rp = 0; rp < NREP; ++rp) {
                const float2 v = bins2[(rp << MAXP) + i];
                sc += v.x; ss += v.y;
            }
            tab2[i] = make_float2(sc, ss);
        }
    }
    __syncthreads();

    // phase B: each wave owns 2 batches; xv via 2 ds_read_b128 per batch;
    // reduction is pure-VALU DPP, store from lane 63.
    const int wave = t >> 6;
    const int lane = t & 63;
    const int bl0  = wave * B_PER_WAVE;

    const float4 a0 = sxPerm4[bl0 * 2],       b0 = sxPerm4[bl0 * 2 + 1];
    const float4 a1 = sxPerm4[(bl0 + 1) * 2], b1 = sxPerm4[(bl0 + 1) * 2 + 1];
    const float xv0[8] = {a0.x, a0.y, a0.z, a0.w, b0.x, b0.y, b0.z, b0.w};
    const float xv1[8] = {a1.x, a1.y, a1.z, a1.w, b1.x, b1.y, b1.z, b1.w};

    float acc0 = 0.0f, acc1 = 0.0f;
    if constexpr (p >= 6) {
        // u = lane + (j<<6): low-6-bit contribution to A is lane-fixed
        float A0 = 0.0f, A1 = 0.0f;
        #pragma unroll
        for (int i = 0; i < 6; ++i) {
            const bool bset = (lane >> i) & 1;
            A0 += bset ? xv0[i] : -xv0[i];
            A1 += bset ? xv1[i] : -xv1[i];
        }
        constexpr int HI = 1 << (p - 6);
        #pragma unroll
        for (int j = 0; j < HI; ++j) {
            float Aj0 = A0, Aj1 = A1;
            #pragma unroll
            for (int i = 6; i < p; ++i) {
                const bool bset = (j >> (i - 6)) & 1;
                Aj0 += bset ? xv0[i] : -xv0[i];
                Aj1 += bset ? xv1[i] : -xv1[i];
            }
            const float2 tv = tab2[lane + (j << 6)];  // shared by both batches
            float s0, c0, s1, c1;
            __sincosf(Aj0, &s0, &c0);
            __sincosf(Aj1, &s1, &c1);
            acc0 = fmaf(c0, tv.x, fmaf(s0, tv.y, acc0));
            acc1 = fmaf(c1, tv.x, fmaf(s1, tv.y, acc1));
        }
    } else {
        if (lane < nb) {
            float A0 = 0.0f, A1 = 0.0f;
            #pragma unroll
            for (int i = 0; i < p; ++i) {
                const bool bset = (lane >> i) & 1;
                A0 += bset ? xv0[i] : -xv0[i];
                A1 += bset ? xv1[i] : -xv1[i];
            }
            const float2 tv = tab2[lane];
            float s0, c0, s1, c1;
            __sincosf(A0, &s0, &c0);
            __sincosf(A1, &s1, &c1);
            acc0 = fmaf(c0, tv.x, fmaf(s0, tv.y, acc0));
            acc1 = fmaf(c1, tv.x, fmaf(s1, tv.y, acc1));
        }
    }

    acc0 = wave64_sum(acc0);
    acc1 = wave64_sum(acc1);
    if (lane == 63) {   // wave sum lands in lane 63 (DPP pattern)
        constexpr float SCALE = 2.0f / (float)DIM;   // 2^-13, exact
        out[(slice * SLICE_B + bl0)     * NQ + Q] = acc0 * SCALE;
        out[(slice * SLICE_B + bl0 + 1) * NQ + Q] = acc1 * SCALE;
    }
}

// -------- single fused kernel: grid = NQ x NSLICE, d_ws unused --------
__global__ __launch_bounds__(TB, 4)
void fused_kernel(const float* __restrict__ x, const float* __restrict__ params,
                  float* __restrict__ out)
{
    __shared__ float2 bins2[NREP << MAXP];       // 32 KB replica bins
    __shared__ float2 tab2[1 << MAXP];           // 2 KB merged table
    __shared__ float4 sxPerm4[SLICE_B * 2];      // 1 KB: x rows permuted by qb[q], padded to 8

    const int q     = blockIdx.x % NQ;
    const int slice = blockIdx.x / NQ;
    const int t     = threadIdx.x;

    // Stage x pre-permuted: sxPerm[b][j] = x[row][qb[q][j]] (j<p), else 0.
    // No bin zero-init needed (writer-indexed merge). Syncs in run_q order
    // these writes before phase B.
    float* sp = (float*)sxPerm4;
    for (int i = t; i < SLICE_B * 8; i += TB) {
        const int b = i >> 3, j = i & 7;
        float v = 0.0f;
        if (j < TAB.p[q])
            v = x[(slice * SLICE_B + b) * NQ + (int)TAB.qb[q][j]];
        sp[i] = v;
    }

    switch (q) {
        case 0:  run_q<0 >(params, bins2, tab2, sxPerm4, out, slice, t); break;
        case 1:  run_q<1 >(params, bins2, tab2, sxPerm4, out, slice, t); break;
        case 2:  run_q<2 >(params, bins2, tab2, sxPerm4, out, slice, t); break;
        case 3:  run_q<3 >(params, bins2, tab2, sxPerm4, out, slice, t); break;
        case 4:  run_q<4 >(params, bins2, tab2, sxPerm4, out, slice, t); break;
        case 5:  run_q<5 >(params, bins2, tab2, sxPerm4, out, slice, t); break;
        case 6:  run_q<6 >(params, bins2, tab2, sxPerm4, out, slice, t); break;
        case 7:  run_q<7 >(params, bins2, tab2, sxPerm4, out, slice, t); break;
        case 8:  run_q<8 >(params, bins2, tab2, sxPerm4, out, slice, t); break;
        case 9:  run_q<9 >(params, bins2, tab2, sxPerm4, out, slice, t); break;
        case 10: run_q<10>(params, bins2, tab2, sxPerm4, out, slice, t); break;
        case 11: run_q<11>(params, bins2, tab2, sxPerm4, out, slice, t); break;
        case 12: run_q<12>(params, bins2, tab2, sxPerm4, out, slice, t); break;
        case 13: run_q<13>(params, bins2, tab2, sxPerm4, out, slice, t); break;
    }
}

extern "C" void kernel_launch(void* const* d_in, const int* in_sizes, int n_in,
                              void* d_out, int out_size, void* d_ws, size_t ws_size,
                              hipStream_t stream) {
    const float* x      = (const float*)d_in[0];   // (512, 14) float32
    const float* params = (const float*)d_in[1];   // (6, 1, 14) float32
    float* out          = (float*)d_out;           // (512, 14) float32
    (void)d_ws; (void)ws_size;                     // workspace intentionally unused

    fused_kernel<<<NQ * NSLICE, TB, 0, stream>>>(x, params, out);
}